// Round 1
// baseline (227.713 us; speedup 1.0000x reference)
//
#include <hip/hip_runtime.h>

typedef _Float16 f16x8 __attribute__((ext_vector_type(8)));
typedef _Float16 f16x4 __attribute__((ext_vector_type(4)));
typedef float f32x4 __attribute__((ext_vector_type(4)));

#define MFMA16(a, b, c) __builtin_amdgcn_mfma_f32_16x16x32_f16(a, b, c, 0, 0, 0)

// ---------------------------------------------------------------- converts
__global__ __launch_bounds__(256) void f32_to_f16_kernel(
    const float* __restrict__ in, _Float16* __restrict__ out, int n) {
  int i = (blockIdx.x * 256 + threadIdx.x) * 4;
  if (i >= n) return;
  float4 v = *(const float4*)(in + i);
  f16x4 h;
  h.x = (_Float16)v.x; h.y = (_Float16)v.y; h.z = (_Float16)v.z; h.w = (_Float16)v.w;
  *(f16x4*)(out + i) = h;
}

// ---------------------------------------------------------------- GEMM core
// C[m,n] = sum_k A[m,k] * W[n,k]   (torch Linear: x @ W^T)
// M=4096, N=1024, K=1024 for every GEMM in this problem.
// 128x128 tile, BK=64, 4 waves in 2x2, each wave 64x64 (4x4 fragments 16x16).
// LDS padded to stride 72 halves (144 B): rows land on banks 4r%32 -> 2-way
// aliasing only (free, m136); 144 % 16 == 0 so ds_{read,write}_b128 stay aligned.
#define LDP 72

__device__ __forceinline__ void stage128x64(const _Float16* __restrict__ g, int ld,
                                            _Float16* s, int tid) {
#pragma unroll
  for (int i = 0; i < 4; ++i) {
    int cid = tid + 256 * i;      // 0..1023 chunks of 8 halves
    int r = cid >> 3;             // 0..127
    int c = (cid & 7) * 8;        // 0..56
    *(int4*)(s + r * LDP + c) = *(const int4*)(g + (size_t)r * ld + c);
  }
}

__device__ __forceinline__ void gemm_core(const _Float16* __restrict__ A,
                                          const _Float16* __restrict__ W,
                                          _Float16* As, _Float16* Bs,
                                          f32x4 acc[4][4], int m0, int n0, int tid) {
  int lane = tid & 63;
  int lr = lane & 15, lg = lane >> 4;
  int wm = ((tid >> 6) >> 1) * 64, wn = ((tid >> 6) & 1) * 64;
  for (int k0 = 0; k0 < 1024; k0 += 64) {
    __syncthreads();
    stage128x64(A + (size_t)m0 * 1024 + k0, 1024, As, tid);
    stage128x64(W + (size_t)n0 * 1024 + k0, 1024, Bs, tid);
    __syncthreads();
#pragma unroll
    for (int ks = 0; ks < 2; ++ks) {
      f16x8 af[4], bfv[4];
#pragma unroll
      for (int mf = 0; mf < 4; ++mf)
        af[mf] = *(const f16x8*)(As + (wm + mf * 16 + lr) * LDP + ks * 32 + lg * 8);
#pragma unroll
      for (int nf = 0; nf < 4; ++nf)
        bfv[nf] = *(const f16x8*)(Bs + (wn + nf * 16 + lr) * LDP + ks * 32 + lg * 8);
#pragma unroll
      for (int mf = 0; mf < 4; ++mf)
#pragma unroll
        for (int nf = 0; nf < 4; ++nf)
          acc[mf][nf] = MFMA16(af[mf], bfv[nf], acc[mf][nf]);
    }
  }
}

// --------------------------------------------------- QKV projection GEMM
// z=0: Q -> [B,H,S,Hd]; z=1: K -> [B,H,S,Hd]; z=2: V -> transposed [B,H,Hd,S]
__global__ __launch_bounds__(256) void proj_gemm(
    const _Float16* __restrict__ xb,
    const _Float16* __restrict__ wq, const _Float16* __restrict__ wk,
    const _Float16* __restrict__ wv,
    const float* __restrict__ bq, const float* __restrict__ bk,
    const float* __restrict__ bv,
    _Float16* __restrict__ qo, _Float16* __restrict__ ko, _Float16* __restrict__ vo) {
  __shared__ __align__(16) _Float16 As[128 * LDP];
  __shared__ __align__(16) _Float16 Bs[128 * LDP];
  int z = blockIdx.z;
  const _Float16* W = (z == 0) ? wq : ((z == 1) ? wk : wv);
  const float* bias = (z == 0) ? bq : ((z == 1) ? bk : bv);
  int tid = threadIdx.x;
  int m0 = blockIdx.y * 128, n0 = blockIdx.x * 128;
  f32x4 acc[4][4] = {};
  gemm_core(xb, W, As, Bs, acc, m0, n0, tid);

  int lane = tid & 63;
  int lr = lane & 15, lg = lane >> 4;
  int wm = ((tid >> 6) >> 1) * 64, wn = ((tid >> 6) & 1) * 64;
#pragma unroll
  for (int nf = 0; nf < 4; ++nf) {
    int col = n0 + wn + nf * 16 + lr;
    float bb = bias[col];
    int h = col >> 6, hd = col & 63;
#pragma unroll
    for (int mf = 0; mf < 4; ++mf) {
#pragma unroll
      for (int i = 0; i < 4; ++i) {
        int row = m0 + wm + mf * 16 + lg * 4 + i;
        int b = row >> 11, s = row & 2047;
        float v = acc[mf][nf][i] + bb;
        if (z == 2) {
          vo[((size_t)(b * 16 + h) * 64 + hd) * 2048 + s] = (_Float16)v;
        } else {
          _Float16* o = (z == 0) ? qo : ko;
          o[((size_t)(b * 16 + h) * 2048 + s) * 64 + hd] = (_Float16)v;
        }
      }
    }
  }
}

// --------------------------------------------------------- output GEMM (f32)
__global__ __launch_bounds__(256) void out_gemm(
    const _Float16* __restrict__ attn, const _Float16* __restrict__ wo,
    const float* __restrict__ bo, float* __restrict__ out) {
  __shared__ __align__(16) _Float16 As[128 * LDP];
  __shared__ __align__(16) _Float16 Bs[128 * LDP];
  int tid = threadIdx.x;
  int m0 = blockIdx.y * 128, n0 = blockIdx.x * 128;
  f32x4 acc[4][4] = {};
  gemm_core(attn, wo, As, Bs, acc, m0, n0, tid);

  int lane = tid & 63;
  int lr = lane & 15, lg = lane >> 4;
  int wm = ((tid >> 6) >> 1) * 64, wn = ((tid >> 6) & 1) * 64;
#pragma unroll
  for (int nf = 0; nf < 4; ++nf) {
    int col = n0 + wn + nf * 16 + lr;
    float bb = bo[col];
#pragma unroll
    for (int mf = 0; mf < 4; ++mf)
#pragma unroll
      for (int i = 0; i < 4; ++i) {
        int row = m0 + wm + mf * 16 + lg * 4 + i;
        out[(size_t)row * 1024 + col] = acc[mf][nf][i] + bb;
      }
  }
}

// --------------------------------------------------------- flash attention
// grid (qtile=32, h=16, b=2), 256 threads = 4 waves, 16 q-rows/wave.
// Q,K: [B,H,S,64]; VT: [B,H,64,S]; O: [B,S,1024] f16.
__global__ __launch_bounds__(256) void attn_kernel(
    const _Float16* __restrict__ Q, const _Float16* __restrict__ K,
    const _Float16* __restrict__ VT, _Float16* __restrict__ O) {
  __shared__ __align__(16) _Float16 Ks[64 * LDP];
  __shared__ __align__(16) _Float16 Vs[64 * LDP];   // [hd][kv] (V transposed)
  __shared__ __align__(16) _Float16 Ps[4][16 * LDP];
  int tid = threadIdx.x, lane = tid & 63, wid = tid >> 6;
  int qt = blockIdx.x, h = blockIdx.y, b = blockIdx.z;
  size_t hoff = (size_t)(b * 16 + h) * 2048 * 64;
  const _Float16* Qh = Q + hoff;
  const _Float16* Kh = K + hoff;
  const _Float16* VTh = VT + hoff;

  int q0 = qt * 64 + wid * 16;      // wave's global q base
  int lr = lane & 15, lg = lane >> 4;

  f16x8 qf[2];
#pragma unroll
  for (int ks = 0; ks < 2; ++ks)
    qf[ks] = *(const f16x8*)(Qh + (size_t)(q0 + lr) * 64 + ks * 32 + lg * 8);

  float m_i[4], l_i[4];
  f32x4 oacc[4] = {};
#pragma unroll
  for (int i = 0; i < 4; ++i) { m_i[i] = -__builtin_inff(); l_i[i] = 0.f; }

  const float SCL = 0.125f;          // 1/sqrt(64)
  const float L2E = 1.44269504f;
  int ntiles = qt + 1;               // causal: kv tiles 0..qt
  for (int t = 0; t < ntiles; ++t) {
    int kv0 = t * 64;
    __syncthreads();
#pragma unroll
    for (int i = 0; i < 2; ++i) {    // stage K (rows=kv) and VT (rows=hd)
      int cid = tid + 256 * i;
      int r = cid >> 3, c = (cid & 7) * 8;
      *(int4*)(Ks + r * LDP + c) = *(const int4*)(Kh + (size_t)(kv0 + r) * 64 + c);
      *(int4*)(Vs + r * LDP + c) = *(const int4*)(VTh + (size_t)r * 2048 + kv0 + c);
    }
    __syncthreads();

    f32x4 sc[4];
#pragma unroll
    for (int nf = 0; nf < 4; ++nf) {
      f16x8 k0v = *(const f16x8*)(Ks + (nf * 16 + lr) * LDP + lg * 8);
      f16x8 k1v = *(const f16x8*)(Ks + (nf * 16 + lr) * LDP + 32 + lg * 8);
      f32x4 z = {0.f, 0.f, 0.f, 0.f};
      z = MFMA16(qf[0], k0v, z);
      z = MFMA16(qf[1], k1v, z);
      sc[nf] = z;
    }
    // scale + causal mask (C layout: col=lr -> key, row=lg*4+i -> query)
#pragma unroll
    for (int nf = 0; nf < 4; ++nf) {
      int kg = kv0 + nf * 16 + lr;
#pragma unroll
      for (int i = 0; i < 4; ++i) {
        float s = sc[nf][i] * SCL;
        int qg = q0 + lg * 4 + i;
        sc[nf][i] = (kg <= qg) ? s : -__builtin_inff();
      }
    }
    // online softmax; row-reduce over the 16 lanes of each row group
    float alpha[4];
#pragma unroll
    for (int i = 0; i < 4; ++i) {
      float mx = fmaxf(fmaxf(sc[0][i], sc[1][i]), fmaxf(sc[2][i], sc[3][i]));
#pragma unroll
      for (int msk = 8; msk >= 1; msk >>= 1)
        mx = fmaxf(mx, __shfl_xor(mx, msk, 16));
      float mn = fmaxf(m_i[i], mx);
      alpha[i] = exp2f((m_i[i] - mn) * L2E);   // exp2(-inf)=0 on first tile
      m_i[i] = mn;
      float ps = 0.f;
#pragma unroll
      for (int nf = 0; nf < 4; ++nf) {
        float p = exp2f((sc[nf][i] - mn) * L2E);
        sc[nf][i] = p;
        ps += p;
      }
#pragma unroll
      for (int msk = 8; msk >= 1; msk >>= 1)
        ps += __shfl_xor(ps, msk, 16);
      l_i[i] = l_i[i] * alpha[i] + ps;
    }
    // P: C layout -> A layout via per-wave LDS scratch
    _Float16* pw = &Ps[wid][0];
#pragma unroll
    for (int nf = 0; nf < 4; ++nf)
#pragma unroll
      for (int i = 0; i < 4; ++i)
        pw[(lg * 4 + i) * LDP + nf * 16 + lr] = (_Float16)sc[nf][i];
    __syncthreads();
#pragma unroll
    for (int nf = 0; nf < 4; ++nf)
#pragma unroll
      for (int i = 0; i < 4; ++i)
        oacc[nf][i] *= alpha[i];
    f16x8 pf0 = *(const f16x8*)(pw + lr * LDP + lg * 8);
    f16x8 pf1 = *(const f16x8*)(pw + lr * LDP + 32 + lg * 8);
#pragma unroll
    for (int nf = 0; nf < 4; ++nf) {
      f16x8 v0 = *(const f16x8*)(Vs + (nf * 16 + lr) * LDP + lg * 8);
      f16x8 v1 = *(const f16x8*)(Vs + (nf * 16 + lr) * LDP + 32 + lg * 8);
      oacc[nf] = MFMA16(pf0, v0, oacc[nf]);
      oacc[nf] = MFMA16(pf1, v1, oacc[nf]);
    }
  }
#pragma unroll
  for (int i = 0; i < 4; ++i) l_i[i] = 1.0f / l_i[i];
#pragma unroll
  for (int nf = 0; nf < 4; ++nf) {
    int hd = nf * 16 + lr;
#pragma unroll
    for (int i = 0; i < 4; ++i) {
      int qg = q0 + lg * 4 + i;
      O[((size_t)b * 2048 + qg) * 1024 + h * 64 + hd] = (_Float16)(oacc[nf][i] * l_i[i]);
    }
  }
}

// ------------------------------------------------------------------- launch
extern "C" void kernel_launch(void* const* d_in, const int* in_sizes, int n_in,
                              void* d_out, int out_size, void* d_ws, size_t ws_size,
                              hipStream_t stream) {
  const float* x  = (const float*)d_in[0];
  const float* Wq = (const float*)d_in[1];
  const float* bq = (const float*)d_in[2];
  const float* Wk = (const float*)d_in[3];
  const float* bk = (const float*)d_in[4];
  const float* Wv = (const float*)d_in[5];
  const float* bv = (const float*)d_in[6];
  const float* Wo = (const float*)d_in[7];
  const float* bo = (const float*)d_in[8];
  float* out = (float*)d_out;

  _Float16* ws  = (_Float16*)d_ws;
  _Float16* xb  = ws;                 // 4194304
  _Float16* wqb = ws + 4194304;       // 1048576
  _Float16* wkb = ws + 5242880;
  _Float16* wvb = ws + 6291456;
  _Float16* wob = ws + 7340032;
  _Float16* qw  = ws + 8388608;       // [B,H,S,64]
  _Float16* kw  = ws + 12582912;      // [B,H,S,64]
  _Float16* vtw = ws + 16777216;      // [B,H,64,S]
  _Float16* aw  = ws + 20971520;      // [B,S,1024]
  // total: 25165824 halves = 48 MiB of d_ws

  f32_to_f16_kernel<<<4096, 256, 0, stream>>>(x, xb, 4194304);
  f32_to_f16_kernel<<<1024, 256, 0, stream>>>(Wq, wqb, 1048576);
  f32_to_f16_kernel<<<1024, 256, 0, stream>>>(Wk, wkb, 1048576);
  f32_to_f16_kernel<<<1024, 256, 0, stream>>>(Wv, wvb, 1048576);
  f32_to_f16_kernel<<<1024, 256, 0, stream>>>(Wo, wob, 1048576);

  proj_gemm<<<dim3(8, 32, 3), 256, 0, stream>>>(xb, wqb, wkb, wvb, bq, bk, bv,
                                                qw, kw, vtw);
  attn_kernel<<<dim3(32, 16, 2), 256, 0, stream>>>(qw, kw, vtw, aw);
  out_gemm<<<dim3(8, 32, 1), 256, 0, stream>>>(aw, wob, bo, out);
}

// Round 3
// 183.534 us; speedup vs baseline: 1.2407x; 1.2407x over previous
//
#include <hip/hip_runtime.h>

typedef _Float16 f16x8 __attribute__((ext_vector_type(8)));
typedef _Float16 f16x4 __attribute__((ext_vector_type(4)));
typedef float f32x4 __attribute__((ext_vector_type(4)));

#define MFMA32(a, b, c) __builtin_amdgcn_mfma_f32_16x16x32_f16(a, b, c, 0, 0, 0)
#define MFMA16(a, b, c) __builtin_amdgcn_mfma_f32_16x16x16f16(a, b, c, 0, 0, 0)

// ---------------------------------------------------------------- converts
__global__ __launch_bounds__(256) void f32_to_f16_kernel(
    const float* __restrict__ in, _Float16* __restrict__ out, int n) {
  int i = (blockIdx.x * 256 + threadIdx.x) * 4;
  if (i >= n) return;
  float4 v = *(const float4*)(in + i);
  f16x4 h;
  h.x = (_Float16)v.x; h.y = (_Float16)v.y; h.z = (_Float16)v.z; h.w = (_Float16)v.w;
  *(f16x4*)(out + i) = h;
}

// ---------------------------------------------------------------- GEMM core
// C[m,n] = sum_k A[m,k] * W[n,k]. 128x128 tile, BK=64, 4 waves 2x2, each 64x64.
// LDS is LINEAR [128][64] halves; staged via global_load_lds width=16 (m97):
// LDS dest is wave-uniform base + lane*16, so dest must be contiguous.
__device__ __forceinline__ void gld_lds16(_Float16* l, const _Float16* g) {
  __builtin_amdgcn_global_load_lds(
      (const __attribute__((address_space(1))) unsigned int*)g,
      (__attribute__((address_space(3))) unsigned int*)l, 16, 0, 0);
}

// stage a 128x64 f16 tile (row stride ldg halves in global) into linear LDS
__device__ __forceinline__ void stage_async(_Float16* lds, const _Float16* g,
                                            int ldg, int wid, int lane) {
#pragma unroll
  for (int j = 0; j < 4; ++j) {
    int blk = wid * 4 + j;                 // 16 blocks of 8 rows x 64 halves
    int row = blk * 8 + (lane >> 3);
    int col = (lane & 7) * 8;
    gld_lds16(lds + blk * 512, g + (size_t)row * ldg + col);  // uniform LDS base
  }
}

__device__ __forceinline__ void gemm_core(const _Float16* __restrict__ A,
                                          const _Float16* __restrict__ W,
                                          _Float16* As, _Float16* Bs,
                                          f32x4 acc[4][4], int m0, int n0, int tid) {
  int lane = tid & 63, wid = tid >> 6;
  int lr = lane & 15, lg = lane >> 4;
  int wm = (wid >> 1) * 64, wn = (wid & 1) * 64;
  for (int k0 = 0; k0 < 1024; k0 += 64) {
    __syncthreads();
    stage_async(As, A + (size_t)m0 * 1024 + k0, 1024, wid, lane);
    stage_async(Bs, W + (size_t)n0 * 1024 + k0, 1024, wid, lane);
    __syncthreads();   // compiler drains vmcnt(0) before s_barrier
#pragma unroll
    for (int ks = 0; ks < 2; ++ks) {
      f16x8 af[4], bfv[4];
#pragma unroll
      for (int mf = 0; mf < 4; ++mf)
        af[mf] = *(const f16x8*)(As + (wm + mf * 16 + lr) * 64 + ks * 32 + lg * 8);
#pragma unroll
      for (int nf = 0; nf < 4; ++nf)
        bfv[nf] = *(const f16x8*)(Bs + (wn + nf * 16 + lr) * 64 + ks * 32 + lg * 8);
#pragma unroll
      for (int mf = 0; mf < 4; ++mf)
#pragma unroll
        for (int nf = 0; nf < 4; ++nf)
          acc[mf][nf] = MFMA32(af[mf], bfv[nf], acc[mf][nf]);
    }
  }
}

// --------------------------------------------------- QKV projection GEMM
__global__ __launch_bounds__(256) void proj_gemm(
    const _Float16* __restrict__ xb,
    const _Float16* __restrict__ wq, const _Float16* __restrict__ wk,
    const _Float16* __restrict__ wv,
    const float* __restrict__ bq, const float* __restrict__ bk,
    const float* __restrict__ bv,
    _Float16* __restrict__ qo, _Float16* __restrict__ ko, _Float16* __restrict__ vo) {
  __shared__ __align__(16) _Float16 As[128 * 64];
  __shared__ __align__(16) _Float16 Bs[128 * 64];
  int z = blockIdx.z;
  const _Float16* W = (z == 0) ? wq : ((z == 1) ? wk : wv);
  const float* bias = (z == 0) ? bq : ((z == 1) ? bk : bv);
  int tid = threadIdx.x;
  int m0 = blockIdx.y * 128, n0 = blockIdx.x * 128;
  f32x4 acc[4][4] = {};
  gemm_core(xb, W, As, Bs, acc, m0, n0, tid);

  int lane = tid & 63;
  int lr = lane & 15, lg = lane >> 4;
  int wm = ((tid >> 6) >> 1) * 64, wn = ((tid >> 6) & 1) * 64;
#pragma unroll
  for (int nf = 0; nf < 4; ++nf) {
    int col = n0 + wn + nf * 16 + lr;
    float bb = bias[col];
    int h = col >> 6, hd = col & 63;
#pragma unroll
    for (int mf = 0; mf < 4; ++mf) {
#pragma unroll
      for (int i = 0; i < 4; ++i) {
        int row = m0 + wm + mf * 16 + lg * 4 + i;
        int b = row >> 11, s = row & 2047;
        float v = acc[mf][nf][i] + bb;
        if (z == 2) {
          vo[((size_t)(b * 16 + h) * 64 + hd) * 2048 + s] = (_Float16)v;
        } else {
          _Float16* o = (z == 0) ? qo : ko;
          o[((size_t)(b * 16 + h) * 2048 + s) * 64 + hd] = (_Float16)v;
        }
      }
    }
  }
}

// --------------------------------------------------------- output GEMM (f32)
__global__ __launch_bounds__(256) void out_gemm(
    const _Float16* __restrict__ attn, const _Float16* __restrict__ wo,
    const float* __restrict__ bo, float* __restrict__ out) {
  __shared__ __align__(16) _Float16 As[128 * 64];
  __shared__ __align__(16) _Float16 Bs[128 * 64];
  int tid = threadIdx.x;
  int m0 = blockIdx.y * 128, n0 = blockIdx.x * 128;
  f32x4 acc[4][4] = {};
  gemm_core(attn, wo, As, Bs, acc, m0, n0, tid);

  int lane = tid & 63;
  int lr = lane & 15, lg = lane >> 4;
  int wm = ((tid >> 6) >> 1) * 64, wn = ((tid >> 6) & 1) * 64;
#pragma unroll
  for (int nf = 0; nf < 4; ++nf) {
    int col = n0 + wn + nf * 16 + lr;
    float bb = bo[col];
#pragma unroll
    for (int mf = 0; mf < 4; ++mf)
#pragma unroll
      for (int i = 0; i < 4; ++i) {
        int row = m0 + wm + mf * 16 + lg * 4 + i;
        out[(size_t)row * 1024 + col] = acc[mf][nf][i] + bb;
      }
  }
}

// --------------------------------------------------------- flash attention v2
// Swapped layout: S^T = mfma(K, Q) so col=q (lane&15), row=kv (lg*4+i).
// Each lane owns ONE q-row; softmax state m,l are scalars; row reduce =
// in-reg + 2 shfl_xor. Lane's 4 P-values per 16-subtile ARE the B-fragment of
// mfma_f32_16x16x16f16 (k=lg*4+j) -> PV needs no transpose/LDS/shuffles.
#define LDP 72  // padded LDS stride for attn tiles (2-way aliasing only)

template <bool DIAG>
__device__ __forceinline__ void attn_tile(const _Float16* Ks, const _Float16* Vs,
                                          const f16x8 qb[2], int kv0, int q0,
                                          int lr, int lg, int nfc,
                                          float& m, float& l, f32x4 ot[4]) {
  const float L2E = 1.44269504f;
  const float NINF = -__builtin_inff();
  f32x4 sc[4];
#pragma unroll
  for (int nf = 0; nf < 4; ++nf) {
    if (!DIAG || nf < nfc) {
      f16x8 k0 = *(const f16x8*)(Ks + (nf * 16 + lr) * LDP + lg * 8);
      f16x8 k1 = *(const f16x8*)(Ks + (nf * 16 + lr) * LDP + 32 + lg * 8);
      f32x4 z = {0.f, 0.f, 0.f, 0.f};
      z = MFMA32(k0, qb[0], z);
      z = MFMA32(k1, qb[1], z);
      sc[nf] = z;
    } else {
      sc[nf] = f32x4{NINF, NINF, NINF, NINF};
    }
  }
  if (DIAG) {
    int qg = q0 + lr;
#pragma unroll
    for (int nf = 0; nf < 4; ++nf)
#pragma unroll
      for (int i = 0; i < 4; ++i) {
        int kg = kv0 + nf * 16 + lg * 4 + i;
        sc[nf][i] = (kg <= qg) ? sc[nf][i] : NINF;
      }
  }
  // row max: 16 in-reg values + lanes {lr, lr+16, lr+32, lr+48}
  f32x4 mx4 = sc[0];
#pragma unroll
  for (int nf = 1; nf < 4; ++nf)
#pragma unroll
    for (int i = 0; i < 4; ++i) mx4[i] = fmaxf(mx4[i], sc[nf][i]);
  float tm = fmaxf(fmaxf(mx4[0], mx4[1]), fmaxf(mx4[2], mx4[3]));
  tm = fmaxf(tm, __shfl_xor(tm, 16));
  tm = fmaxf(tm, __shfl_xor(tm, 32));
  float mn = fmaxf(m, tm);
  float alpha = __builtin_amdgcn_exp2f((m - mn) * L2E);
  m = mn;
  float mnL = mn * L2E;
  float ps = 0.f;
  f16x4 pf[4];
#pragma unroll
  for (int nf = 0; nf < 4; ++nf) {
#pragma unroll
    for (int i = 0; i < 4; ++i) {
      float p = __builtin_amdgcn_exp2f(sc[nf][i] * L2E - mnL);
      ps += p;
      pf[nf][i] = (_Float16)p;
    }
  }
  ps += __shfl_xor(ps, 16);
  ps += __shfl_xor(ps, 32);
  l = l * alpha + ps;
#pragma unroll
  for (int dt = 0; dt < 4; ++dt)
#pragma unroll
    for (int i = 0; i < 4; ++i) ot[dt][i] *= alpha;
  // PV: O^T[d][q] += V^T . P^T, K=16 per subtile, B-frag = pf[nf] directly
#pragma unroll
  for (int nf = 0; nf < 4; ++nf) {
    if (!DIAG || nf < nfc) {
#pragma unroll
      for (int dt = 0; dt < 4; ++dt) {
        f16x4 vf = *(const f16x4*)(Vs + (dt * 16 + lr) * LDP + nf * 16 + lg * 4);
        ot[dt] = MFMA16(vf, pf[nf], ot[dt]);
      }
    }
  }
}

__global__ __launch_bounds__(256) void attn_kernel(
    const _Float16* __restrict__ Q, const _Float16* __restrict__ K,
    const _Float16* __restrict__ VT, _Float16* __restrict__ O) {
  __shared__ __align__(16) _Float16 Ks[64 * LDP];
  __shared__ __align__(16) _Float16 Vs[64 * LDP];   // [hd][kv] (V transposed)
  int tid = threadIdx.x, lane = tid & 63, wid = tid >> 6;
  int qt = 31 - blockIdx.x;            // LPT: longest blocks dispatch first
  int h = blockIdx.y, b = blockIdx.z;
  size_t hoff = (size_t)(b * 16 + h) * 2048 * 64;
  const _Float16* Qh = Q + hoff;
  const _Float16* Kh = K + hoff;
  const _Float16* VTh = VT + hoff;
  int q0 = qt * 64 + wid * 16;
  int lr = lane & 15, lg = lane >> 4;

  f16x8 qb[2];
  qb[0] = *(const f16x8*)(Qh + (size_t)(q0 + lr) * 64 + lg * 8);
  qb[1] = *(const f16x8*)(Qh + (size_t)(q0 + lr) * 64 + 32 + lg * 8);
#pragma unroll
  for (int j = 0; j < 8; ++j) {        // fold 1/sqrt(64) into Q (exact: 2^-3)
    qb[0][j] *= (_Float16)0.125f;
    qb[1][j] *= (_Float16)0.125f;
  }

  float m = -__builtin_inff(), l = 0.f;
  f32x4 ot[4] = {};                    // O^T acc: d = dt*16+lg*4+i, q = q0+lr

  for (int t = 0; t < qt; ++t) {       // full (unmasked) tiles
    int kv0 = t * 64;
    __syncthreads();
#pragma unroll
    for (int i = 0; i < 2; ++i) {
      int cid = tid + 256 * i;
      int r = cid >> 3, c = (cid & 7) * 8;
      *(int4*)(Ks + r * LDP + c) = *(const int4*)(Kh + (size_t)(kv0 + r) * 64 + c);
      *(int4*)(Vs + r * LDP + c) = *(const int4*)(VTh + (size_t)r * 2048 + kv0 + c);
    }
    __syncthreads();
    attn_tile<false>(Ks, Vs, qb, kv0, q0, lr, lg, 4, m, l, ot);
  }
  {                                    // diagonal tile (masked, per-wave skip)
    int kv0 = qt * 64;
    __syncthreads();
#pragma unroll
    for (int i = 0; i < 2; ++i) {
      int cid = tid + 256 * i;
      int r = cid >> 3, c = (cid & 7) * 8;
      *(int4*)(Ks + r * LDP + c) = *(const int4*)(Kh + (size_t)(kv0 + r) * 64 + c);
      *(int4*)(Vs + r * LDP + c) = *(const int4*)(VTh + (size_t)r * 2048 + kv0 + c);
    }
    __syncthreads();
    attn_tile<true>(Ks, Vs, qb, kv0, q0, lr, lg, wid + 1, m, l, ot);
  }

  float inv = 1.f / l;
  _Float16* Oh = O + ((size_t)b * 2048 + q0 + lr) * 1024 + h * 64;
#pragma unroll
  for (int dt = 0; dt < 4; ++dt) {
    f16x4 o;
#pragma unroll
    for (int i = 0; i < 4; ++i) o[i] = (_Float16)(ot[dt][i] * inv);
    *(f16x4*)(Oh + dt * 16 + lg * 4) = o;
  }
}

// ------------------------------------------------------------------- launch
extern "C" void kernel_launch(void* const* d_in, const int* in_sizes, int n_in,
                              void* d_out, int out_size, void* d_ws, size_t ws_size,
                              hipStream_t stream) {
  const float* x  = (const float*)d_in[0];
  const float* Wq = (const float*)d_in[1];
  const float* bq = (const float*)d_in[2];
  const float* Wk = (const float*)d_in[3];
  const float* bk = (const float*)d_in[4];
  const float* Wv = (const float*)d_in[5];
  const float* bv = (const float*)d_in[6];
  const float* Wo = (const float*)d_in[7];
  const float* bo = (const float*)d_in[8];
  float* out = (float*)d_out;

  _Float16* ws  = (_Float16*)d_ws;
  _Float16* xb  = ws;                 // 4194304
  _Float16* wqb = ws + 4194304;
  _Float16* wkb = ws + 5242880;
  _Float16* wvb = ws + 6291456;
  _Float16* wob = ws + 7340032;
  _Float16* qw  = ws + 8388608;       // [B,H,S,64]
  _Float16* kw  = ws + 12582912;      // [B,H,S,64]
  _Float16* vtw = ws + 16777216;      // [B,H,64,S]
  _Float16* aw  = ws + 20971520;      // [B,S,1024]

  f32_to_f16_kernel<<<4096, 256, 0, stream>>>(x, xb, 4194304);
  f32_to_f16_kernel<<<1024, 256, 0, stream>>>(Wq, wqb, 1048576);
  f32_to_f16_kernel<<<1024, 256, 0, stream>>>(Wk, wkb, 1048576);
  f32_to_f16_kernel<<<1024, 256, 0, stream>>>(Wv, wvb, 1048576);
  f32_to_f16_kernel<<<1024, 256, 0, stream>>>(Wo, wob, 1048576);

  proj_gemm<<<dim3(8, 32, 3), 256, 0, stream>>>(xb, wqb, wkb, wvb, bq, bk, bv,
                                                qw, kw, vtw);
  attn_kernel<<<dim3(32, 16, 2), 256, 0, stream>>>(qw, kw, vtw, aw);
  out_gemm<<<dim3(8, 32, 1), 256, 0, stream>>>(aw, wob, bo, out);
}

// Round 5
// 177.744 us; speedup vs baseline: 1.2811x; 1.0326x over previous
//
#include <hip/hip_runtime.h>

typedef _Float16 f16x8 __attribute__((ext_vector_type(8)));
typedef _Float16 f16x4 __attribute__((ext_vector_type(4)));
typedef float f32x4 __attribute__((ext_vector_type(4)));

#define MFMA32(a, b, c) __builtin_amdgcn_mfma_f32_16x16x32_f16(a, b, c, 0, 0, 0)
#define MFMA16(a, b, c) __builtin_amdgcn_mfma_f32_16x16x16f16(a, b, c, 0, 0, 0)

// ---------------------------------------------------------------- converts
__global__ __launch_bounds__(256) void f32_to_f16_kernel(
    const float* __restrict__ in, _Float16* __restrict__ out, int n) {
  int i = (blockIdx.x * 256 + threadIdx.x) * 4;
  if (i >= n) return;
  float4 v = *(const float4*)(in + i);
  f16x4 h;
  h.x = (_Float16)v.x; h.y = (_Float16)v.y; h.z = (_Float16)v.z; h.w = (_Float16)v.w;
  *(f16x4*)(out + i) = h;
}

// all four 1024x1024 weights in one launch (blockIdx.y selects)
__global__ __launch_bounds__(256) void w_to_f16_kernel(
    const float* __restrict__ w0, const float* __restrict__ w1,
    const float* __restrict__ w2, const float* __restrict__ w3,
    _Float16* __restrict__ o0, _Float16* __restrict__ o1,
    _Float16* __restrict__ o2, _Float16* __restrict__ o3) {
  int z = blockIdx.y;
  const float* in = (z == 0) ? w0 : (z == 1) ? w1 : (z == 2) ? w2 : w3;
  _Float16* out = (z == 0) ? o0 : (z == 1) ? o1 : (z == 2) ? o2 : o3;
  int i = (blockIdx.x * 256 + threadIdx.x) * 4;
  float4 v = *(const float4*)(in + i);
  f16x4 h;
  h.x = (_Float16)v.x; h.y = (_Float16)v.y; h.z = (_Float16)v.z; h.w = (_Float16)v.w;
  *(f16x4*)(out + i) = h;
}

// ---------------------------------------------------------------- GEMM core
// C[m,n] = sum_k A[m,k] * W[n,k]. 128x128 tile, BK=64, 4 waves 2x2, each 64x64.
// LDS LINEAR [128][64]; staged via global_load_lds width=16 (m97 structure).
__device__ __forceinline__ void gld_lds16(_Float16* l, const _Float16* g) {
  __builtin_amdgcn_global_load_lds(
      (const __attribute__((address_space(1))) unsigned int*)g,
      (__attribute__((address_space(3))) unsigned int*)l, 16, 0, 0);
}

__device__ __forceinline__ void stage_async(_Float16* lds, const _Float16* g,
                                            int ldg, int wid, int lane) {
#pragma unroll
  for (int j = 0; j < 4; ++j) {
    int blk = wid * 4 + j;                 // 16 blocks of 8 rows x 64 halves
    int row = blk * 8 + (lane >> 3);
    int col = (lane & 7) * 8;
    gld_lds16(lds + blk * 512, g + (size_t)row * ldg + col);  // uniform LDS base
  }
}

__device__ __forceinline__ void gemm_core(const _Float16* __restrict__ A,
                                          const _Float16* __restrict__ W,
                                          _Float16* As, _Float16* Bs,
                                          f32x4 acc[4][4], int m0, int n0, int tid) {
  int lane = tid & 63, wid = tid >> 6;
  int lr = lane & 15, lg = lane >> 4;
  int wm = (wid >> 1) * 64, wn = (wid & 1) * 64;
  for (int k0 = 0; k0 < 1024; k0 += 64) {
    __syncthreads();
    stage_async(As, A + (size_t)m0 * 1024 + k0, 1024, wid, lane);
    stage_async(Bs, W + (size_t)n0 * 1024 + k0, 1024, wid, lane);
    __syncthreads();
#pragma unroll
    for (int ks = 0; ks < 2; ++ks) {
      f16x8 af[4], bfv[4];
#pragma unroll
      for (int mf = 0; mf < 4; ++mf)
        af[mf] = *(const f16x8*)(As + (wm + mf * 16 + lr) * 64 + ks * 32 + lg * 8);
#pragma unroll
      for (int nf = 0; nf < 4; ++nf)
        bfv[nf] = *(const f16x8*)(Bs + (wn + nf * 16 + lr) * 64 + ks * 32 + lg * 8);
#pragma unroll
      for (int mf = 0; mf < 4; ++mf)
#pragma unroll
        for (int nf = 0; nf < 4; ++nf)
          acc[mf][nf] = MFMA32(af[mf], bfv[nf], acc[mf][nf]);
    }
  }
}

// --------------------------------------------------- QKV projection GEMM
__global__ __launch_bounds__(256) void proj_gemm(
    const _Float16* __restrict__ xb,
    const _Float16* __restrict__ wq, const _Float16* __restrict__ wk,
    const _Float16* __restrict__ wv,
    const float* __restrict__ bq, const float* __restrict__ bk,
    const float* __restrict__ bv,
    _Float16* __restrict__ qo, _Float16* __restrict__ ko, _Float16* __restrict__ vo) {
  __shared__ __align__(16) _Float16 As[128 * 64];
  __shared__ __align__(16) _Float16 Bs[128 * 64];
  int z = blockIdx.z;
  const _Float16* W = (z == 0) ? wq : ((z == 1) ? wk : wv);
  const float* bias = (z == 0) ? bq : ((z == 1) ? bk : bv);
  int tid = threadIdx.x;
  int m0 = blockIdx.y * 128, n0 = blockIdx.x * 128;
  f32x4 acc[4][4] = {};
  gemm_core(xb, W, As, Bs, acc, m0, n0, tid);

  int lane = tid & 63;
  int lr = lane & 15, lg = lane >> 4;
  int wm = ((tid >> 6) >> 1) * 64, wn = ((tid >> 6) & 1) * 64;
#pragma unroll
  for (int nf = 0; nf < 4; ++nf) {
    int col = n0 + wn + nf * 16 + lr;
    float bb = bias[col];
    int h = col >> 6, hd = col & 63;
#pragma unroll
    for (int mf = 0; mf < 4; ++mf) {
#pragma unroll
      for (int i = 0; i < 4; ++i) {
        int row = m0 + wm + mf * 16 + lg * 4 + i;
        int b = row >> 11, s = row & 2047;
        float v = acc[mf][nf][i] + bb;
        if (z == 2) {
          vo[((size_t)(b * 16 + h) * 64 + hd) * 2048 + s] = (_Float16)v;
        } else {
          _Float16* o = (z == 0) ? qo : ko;
          o[((size_t)(b * 16 + h) * 2048 + s) * 64 + hd] = (_Float16)v;
        }
      }
    }
  }
}

// --------------------------------------------------------- output GEMM (f32)
__global__ __launch_bounds__(256) void out_gemm(
    const _Float16* __restrict__ attn, const _Float16* __restrict__ wo,
    const float* __restrict__ bo, float* __restrict__ out) {
  __shared__ __align__(16) _Float16 As[128 * 64];
  __shared__ __align__(16) _Float16 Bs[128 * 64];
  int tid = threadIdx.x;
  int m0 = blockIdx.y * 128, n0 = blockIdx.x * 128;
  f32x4 acc[4][4] = {};
  gemm_core(attn, wo, As, Bs, acc, m0, n0, tid);

  int lane = tid & 63;
  int lr = lane & 15, lg = lane >> 4;
  int wm = ((tid >> 6) >> 1) * 64, wn = ((tid >> 6) & 1) * 64;
#pragma unroll
  for (int nf = 0; nf < 4; ++nf) {
    int col = n0 + wn + nf * 16 + lr;
    float bb = bo[col];
#pragma unroll
    for (int mf = 0; mf < 4; ++mf)
#pragma unroll
      for (int i = 0; i < 4; ++i) {
        int row = m0 + wm + mf * 16 + lg * 4 + i;
        out[(size_t)row * 1024 + col] = acc[mf][nf][i] + bb;
      }
  }
}

// --------------------------------------------------------- flash attention v5
// 4 waves x 32 q-rows = QBLK 128. Swapped scores (col=q); each lane owns two
// q-rows (halves h=0,1) sharing K-frags, V-frags and staged tiles. Per-tile
// math is EXACTLY the round-3 (passed) sequence: always-rescale, full mask.
// Tiles entirely above a wave's diagonal are provable no-ops (all -inf ->
// alpha=1, p=0), so all waves run uniform control flow over all tiles.
#define LDP 72  // padded LDS stride (halves)

template <bool MASK>
__device__ __forceinline__ void attn_tile32(const _Float16* Ks, const _Float16* Vs,
                                            const f16x8 qb[2][2], int kv0, int qwb,
                                            int lr, int lg,
                                            float m[2], float l[2], f32x4 ot[2][4]) {
  const float L2E = 1.44269504f;
  const float NINF = -__builtin_inff();
  f16x8 kf0[4], kf1[4];
#pragma unroll
  for (int nf = 0; nf < 4; ++nf) {
    kf0[nf] = *(const f16x8*)(Ks + (nf * 16 + lr) * LDP + lg * 8);
    kf1[nf] = *(const f16x8*)(Ks + (nf * 16 + lr) * LDP + 32 + lg * 8);
  }
  f32x4 sc[2][4];
#pragma unroll
  for (int h = 0; h < 2; ++h)
#pragma unroll
    for (int nf = 0; nf < 4; ++nf) {
      f32x4 z = {0.f, 0.f, 0.f, 0.f};
      z = MFMA32(kf0[nf], qb[h][0], z);
      z = MFMA32(kf1[nf], qb[h][1], z);
      sc[h][nf] = z;
    }
  if (MASK) {
#pragma unroll
    for (int h = 0; h < 2; ++h) {
      int qg = qwb + h * 16 + lr;
#pragma unroll
      for (int nf = 0; nf < 4; ++nf)
#pragma unroll
        for (int i = 0; i < 4; ++i) {
          int kg = kv0 + nf * 16 + lg * 4 + i;
          sc[h][nf][i] = (kg <= qg) ? sc[h][nf][i] : NINF;
        }
    }
  }
  f16x4 pf[2][4];
#pragma unroll
  for (int h = 0; h < 2; ++h) {
    f32x4 mx4 = sc[h][0];
#pragma unroll
    for (int nf = 1; nf < 4; ++nf)
#pragma unroll
      for (int i = 0; i < 4; ++i) mx4[i] = fmaxf(mx4[i], sc[h][nf][i]);
    float tm = fmaxf(fmaxf(mx4[0], mx4[1]), fmaxf(mx4[2], mx4[3]));
    tm = fmaxf(tm, __shfl_xor(tm, 16));
    tm = fmaxf(tm, __shfl_xor(tm, 32));
    float mn = fmaxf(m[h], tm);
    float alpha = __builtin_amdgcn_exp2f((m[h] - mn) * L2E);
    m[h] = mn;
    float mnL = mn * L2E;
    float ps = 0.f;
#pragma unroll
    for (int nf = 0; nf < 4; ++nf)
#pragma unroll
      for (int i = 0; i < 4; ++i) {
        float p = __builtin_amdgcn_exp2f(sc[h][nf][i] * L2E - mnL);
        ps += p;
        pf[h][nf][i] = (_Float16)p;
      }
    ps += __shfl_xor(ps, 16);
    ps += __shfl_xor(ps, 32);
    l[h] = l[h] * alpha + ps;
#pragma unroll
    for (int dt = 0; dt < 4; ++dt)
#pragma unroll
      for (int i = 0; i < 4; ++i) ot[h][dt][i] *= alpha;
  }
  // PV: V-frags shared by both halves; B-frag = pf directly (K=16)
#pragma unroll
  for (int nf = 0; nf < 4; ++nf)
#pragma unroll
    for (int dt = 0; dt < 4; ++dt) {
      f16x4 vf = *(const f16x4*)(Vs + (dt * 16 + lr) * LDP + nf * 16 + lg * 4);
      ot[0][dt] = MFMA16(vf, pf[0][nf], ot[0][dt]);
      ot[1][dt] = MFMA16(vf, pf[1][nf], ot[1][dt]);
    }
}

__global__ __launch_bounds__(256) void attn_kernel(
    const _Float16* __restrict__ Q, const _Float16* __restrict__ K,
    const _Float16* __restrict__ VT, _Float16* __restrict__ O) {
  __shared__ __align__(16) _Float16 Ks[64 * LDP];
  __shared__ __align__(16) _Float16 Vs[64 * LDP];   // [hd][kv] (V transposed)
  int tid = threadIdx.x, lane = tid & 63, wid = tid >> 6;
  int qt = 15 - blockIdx.x;            // LPT: longest blocks dispatch first
  int hh = blockIdx.y, b = blockIdx.z;
  size_t hoff = (size_t)(b * 16 + hh) * 2048 * 64;
  const _Float16* Qh = Q + hoff;
  const _Float16* Kh = K + hoff;
  const _Float16* VTh = VT + hoff;
  int qwb = qt * 128 + wid * 32;       // wave q base (32 rows)
  int lr = lane & 15, lg = lane >> 4;

  f16x8 qb[2][2];
#pragma unroll
  for (int h = 0; h < 2; ++h) {
    const _Float16* qp = Qh + (size_t)(qwb + h * 16 + lr) * 64;
    qb[h][0] = *(const f16x8*)(qp + lg * 8);
    qb[h][1] = *(const f16x8*)(qp + 32 + lg * 8);
#pragma unroll
    for (int j = 0; j < 8; ++j) {      // fold 1/sqrt(64) into Q (exact: 2^-3)
      qb[h][0][j] *= (_Float16)0.125f;
      qb[h][1][j] *= (_Float16)0.125f;
    }
  }

  float m[2] = {-__builtin_inff(), -__builtin_inff()};
  float l[2] = {0.f, 0.f};
  f32x4 ot[2][4] = {};                 // O^T acc: d = dt*16+lg*4+i, q per half

  int aw = qwb >> 6;                   // first tile needing a mask for this wave
  int ntiles = 2 * qt + 2;             // tiles staged by the block
  for (int t = 0; t < ntiles; ++t) {
    int kv0 = t * 64;
    __syncthreads();
#pragma unroll
    for (int i = 0; i < 2; ++i) {      // stage K (rows=kv) and VT (rows=hd)
      int cid = tid + 256 * i;
      int r = cid >> 3, c = (cid & 7) * 8;
      *(int4*)(Ks + r * LDP + c) = *(const int4*)(Kh + (size_t)(kv0 + r) * 64 + c);
      *(int4*)(Vs + r * LDP + c) = *(const int4*)(VTh + (size_t)r * 2048 + kv0 + c);
    }
    __syncthreads();
    if (t < aw) {
      attn_tile32<false>(Ks, Vs, qb, kv0, qwb, lr, lg, m, l, ot);
    } else {
      attn_tile32<true>(Ks, Vs, qb, kv0, qwb, lr, lg, m, l, ot);
    }
  }

#pragma unroll
  for (int h = 0; h < 2; ++h) {
    float inv = 1.f / l[h];
    _Float16* Oh = O + ((size_t)b * 2048 + qwb + h * 16 + lr) * 1024 + hh * 64;
#pragma unroll
    for (int dt = 0; dt < 4; ++dt) {
      f16x4 o;
#pragma unroll
      for (int i = 0; i < 4; ++i) o[i] = (_Float16)(ot[h][dt][i] * inv);
      *(f16x4*)(Oh + dt * 16 + lg * 4) = o;
    }
  }
}

// ------------------------------------------------------------------- launch
extern "C" void kernel_launch(void* const* d_in, const int* in_sizes, int n_in,
                              void* d_out, int out_size, void* d_ws, size_t ws_size,
                              hipStream_t stream) {
  const float* x  = (const float*)d_in[0];
  const float* Wq = (const float*)d_in[1];
  const float* bq = (const float*)d_in[2];
  const float* Wk = (const float*)d_in[3];
  const float* bk = (const float*)d_in[4];
  const float* Wv = (const float*)d_in[5];
  const float* bv = (const float*)d_in[6];
  const float* Wo = (const float*)d_in[7];
  const float* bo = (const float*)d_in[8];
  float* out = (float*)d_out;

  _Float16* ws  = (_Float16*)d_ws;
  _Float16* xb  = ws;                 // 4194304
  _Float16* wqb = ws + 4194304;
  _Float16* wkb = ws + 5242880;
  _Float16* wvb = ws + 6291456;
  _Float16* wob = ws + 7340032;
  _Float16* qw  = ws + 8388608;       // [B,H,S,64]
  _Float16* kw  = ws + 12582912;      // [B,H,S,64]
  _Float16* vtw = ws + 16777216;      // [B,H,64,S]
  _Float16* aw  = ws + 20971520;      // [B,S,1024]

  f32_to_f16_kernel<<<4096, 256, 0, stream>>>(x, xb, 4194304);
  w_to_f16_kernel<<<dim3(1024, 4), 256, 0, stream>>>(Wq, Wk, Wv, Wo,
                                                     wqb, wkb, wvb, wob);

  proj_gemm<<<dim3(8, 32, 3), 256, 0, stream>>>(xb, wqb, wkb, wvb, bq, bk, bv,
                                                qw, kw, vtw);
  attn_kernel<<<dim3(16, 16, 2), 256, 0, stream>>>(qw, kw, vtw, aw);
  out_gemm<<<dim3(8, 32, 1), 256, 0, stream>>>(aw, wob, bo, out);
}